// Round 4
// baseline (168.857 us; speedup 1.0000x reference)
//
#include <hip/hip_runtime.h>
#include <hip/hip_bf16.h>
#include <math.h>
#include <stdint.h>

#define EPS 1e-5f

typedef __attribute__((ext_vector_type(8))) short bf16x8;
typedef __attribute__((ext_vector_type(16))) float f32x16;

__device__ __forceinline__ ushort f2bf(float f) {
    union { float f; unsigned u; } v; v.f = f;
    unsigned r = (v.u + 0x7FFFu + ((v.u >> 16) & 1u)) >> 16;
    return (ushort)r;
}

__device__ __forceinline__ void dma16(const void* g, void* l) {
    __builtin_amdgcn_global_load_lds(
        (__attribute__((address_space(1))) const void*)(uintptr_t)g,
        (__attribute__((address_space(3))) void*)(uintptr_t)l,
        16, 0, 0);
}

// ---------------------------------------------------------------------------
// Kernel 1: transpose x -> xT[b][y 66][c 66][ic 128] bf16 (borders zero),
// plus pooling partials [b][y][ic].  grid = 2048 blocks, XCD-grouped by sample.
// ---------------------------------------------------------------------------
__global__ __launch_bounds__(256) void transpose_kernel(const float* __restrict__ x,
                                                        ushort* __restrict__ xT,
                                                        float* __restrict__ partial) {
    __shared__ float T[128][65];
    int bid = blockIdx.x;
    int b = (bid & 7) * 4 + (bid >> 9);      // sample -> XCD grouping
    int y = (bid >> 3) & 63;
    int t = threadIdx.x;

    // phase 1: load x[b][ic][y][:], sum, stash in LDS
    int ic2 = t >> 1, half = t & 1;
    const float4* src = (const float4*)(x + (((size_t)b * 128 + ic2) * 64 + y) * 64 + half * 32);
    float s = 0.f;
#pragma unroll
    for (int i = 0; i < 8; ++i) {
        float4 v = src[i];
        int c0 = half * 32 + i * 4;
        T[ic2][c0] = v.x; T[ic2][c0 + 1] = v.y; T[ic2][c0 + 2] = v.z; T[ic2][c0 + 3] = v.w;
        s += v.x + v.y + v.z + v.w;
    }
    s += __shfl_xor(s, 1, 64);
    if (half == 0) partial[((size_t)b * 64 + y) * 128 + ic2] = s;
    __syncthreads();

    // phase 2: write xT[b][y+1][col+1][ic] bf16
    int col = t >> 2, icq = t & 3;
    uint pk[16];
#pragma unroll
    for (int j = 0; j < 16; ++j) {
        float f0 = T[icq * 32 + 2 * j][col];
        float f1 = T[icq * 32 + 2 * j + 1][col];
        pk[j] = (uint)f2bf(f0) | ((uint)f2bf(f1) << 16);
    }
    ushort* dst = xT + ((((size_t)b * 66 + y + 1) * 66) + col + 1) * 128 + icq * 32;
    ((uint4*)dst)[0] = make_uint4(pk[0], pk[1], pk[2], pk[3]);
    ((uint4*)dst)[1] = make_uint4(pk[4], pk[5], pk[6], pk[7]);
    ((uint4*)dst)[2] = make_uint4(pk[8], pk[9], pk[10], pk[11]);
    ((uint4*)dst)[3] = make_uint4(pk[12], pk[13], pk[14], pk[15]);

    uint4 z = make_uint4(0, 0, 0, 0);
    if (y == 0) {
        uint4* row0 = (uint4*)(xT + ((size_t)b * 66 + 0) * 66 * 128);
        for (int i = t; i < 1056; i += 256) row0[i] = z;
    }
    if (y == 63) {
        uint4* row65 = (uint4*)(xT + ((size_t)b * 66 + 65) * 66 * 128);
        for (int i = t; i < 1056; i += 256) row65[i] = z;
    }
    if (t < 32) {
        int c = (t >> 4) * 65;
        int i = t & 15;
        *(uint4*)(xT + ((((size_t)b * 66 + y + 1) * 66) + c) * 128 + i * 8) = z;
    }
}

// ---------------------------------------------------------------------------
// Kernel 2: fused reduce + SE MLP -> att[32,4].  grid = 32 blocks (one/sample).
// ---------------------------------------------------------------------------
__global__ __launch_bounds__(256) void sefuse_kernel(const float* __restrict__ partial,
                                                     const float* __restrict__ se_w1,
                                                     const float* __restrict__ gn1_s, const float* __restrict__ gn1_b,
                                                     const float* __restrict__ se_w2,
                                                     const float* __restrict__ gn2_s, const float* __restrict__ gn2_b,
                                                     float* __restrict__ att) {
    __shared__ float sA[256];
    __shared__ float pl[128];
    __shared__ float h1s[8];
    int b = blockIdx.x;
    int t = threadIdx.x;
    int ic = t & 127, hf = t >> 7;

    const float* p = partial + ((size_t)b * 64 + hf * 32) * 128 + ic;
    float s = 0.f;
#pragma unroll
    for (int k = 0; k < 32; ++k) s += p[k * 128];
    sA[t] = s;
    __syncthreads();
    if (t < 128) pl[t] = (sA[t] + sA[t + 128]) * (1.0f / 4096.0f);
    __syncthreads();
    if (t < 8) {
        float s1 = 0.f;
        for (int c = 0; c < 128; ++c) s1 += pl[c] * se_w1[t * 128 + c];
        h1s[t] = s1;
    }
    __syncthreads();
    if (t == 0) {
        float h1[8];
#pragma unroll
        for (int j = 0; j < 8; ++j) h1[j] = h1s[j];
        float m = 0.f;
#pragma unroll
        for (int j = 0; j < 8; ++j) m += h1[j];
        m *= 0.125f;
        float var = 0.f;
#pragma unroll
        for (int j = 0; j < 8; ++j) { float d = h1[j] - m; var += d * d; }
        var *= 0.125f;
        float inv = rsqrtf(var + EPS);
#pragma unroll
        for (int j = 0; j < 8; ++j) {
            float tt = (h1[j] - m) * inv * gn1_s[j] + gn1_b[j];
            float sp = (tt > 20.f) ? tt : log1pf(expf(tt));
            h1[j] = tt * tanhf(sp);
        }
        float h2[4];
#pragma unroll
        for (int k = 0; k < 4; ++k) {
            float s2 = 0.f;
#pragma unroll
            for (int j = 0; j < 8; ++j) s2 += h1[j] * se_w2[k * 8 + j];
            h2[k] = s2;
        }
        float m2 = 0.25f * (h2[0] + h2[1] + h2[2] + h2[3]);
        float v2 = 0.f;
#pragma unroll
        for (int k = 0; k < 4; ++k) { float d = h2[k] - m2; v2 += d * d; }
        v2 *= 0.25f;
        float inv2 = rsqrtf(v2 + EPS);
#pragma unroll
        for (int k = 0; k < 4; ++k) {
            float tt = (h2[k] - m2) * inv2 * gn2_s[k] + gn2_b[k];
            att[b * 4 + k] = 1.0f / (1.0f + expf(-tt));
        }
    }
}

// ---------------------------------------------------------------------------
// Kernel 3: aggregate weights -> bf16, 32x32x16 A-fragment-major.
// cid = ((h*9+s)*4 + icb)*4 + M32 ; lane l: oc = M32*32+(l&31),
// ic = h*64 + icb*16 + (l>>5)*8 + j.  aggw[((b*288+cid)*64+l)*8+j]
// ---------------------------------------------------------------------------
__global__ __launch_bounds__(256) void aggw_kernel(const float* __restrict__ weight,
                                                   const float* __restrict__ att,
                                                   ushort* __restrict__ aggw) {
    int t = blockIdx.x * 256 + threadIdx.x;     // 72*256 = 18432 = 288*64
    int l = t & 63;
    int cid = t >> 6;                            // 0..287
    int M32 = cid & 3;
    int rest = cid >> 2;
    int icb = rest & 3;
    int hs = rest >> 2;                          // 0..17
    int s = hs % 9;
    int h = hs / 9;
    int oc = M32 * 32 + (l & 31);
    int ic0 = h * 64 + icb * 16 + (l >> 5) * 8;

    float wv[4][8];
#pragma unroll
    for (int k = 0; k < 4; ++k)
#pragma unroll
        for (int j = 0; j < 8; ++j)
            wv[k][j] = weight[(((size_t)(k * 128 + oc)) * 128 + ic0 + j) * 9 + s];

    for (int b = 0; b < 32; ++b) {
        float a0 = att[b * 4 + 0], a1 = att[b * 4 + 1], a2 = att[b * 4 + 2], a3 = att[b * 4 + 3];
        uint pk[4];
#pragma unroll
        for (int p = 0; p < 4; ++p) {
            float f0 = a0 * wv[0][2 * p] + a1 * wv[1][2 * p] + a2 * wv[2][2 * p] + a3 * wv[3][2 * p];
            float f1 = a0 * wv[0][2 * p + 1] + a1 * wv[1][2 * p + 1] + a2 * wv[2][2 * p + 1] + a3 * wv[3][2 * p + 1];
            pk[p] = (uint)f2bf(f0) | ((uint)f2bf(f1) << 16);
        }
        *(uint4*)(aggw + ((size_t)(b * 288 + cid) * 64 + l) * 8) = make_uint4(pk[0], pk[1], pk[2], pk[3]);
    }
}

// ---------------------------------------------------------------------------
// Kernel 4: implicit-GEMM conv, mfma_f32_32x32x16_bf16, 8-row tiles.
// grid 256 = 32 b * 8 row-tiles; block = 256 thr = 4 waves (wn = row-pair).
// Each wave: full 128 oc x 128 px (acc[4][4] f32x16).  1 block/CU.
// LDS [10 rows][66 c][64 ic-half], DMA-staged, swz(c) = (c ^ c>>3) & 7.
// ---------------------------------------------------------------------------
__global__ __launch_bounds__(256, 1) void conv_kernel(const ushort* __restrict__ xT,
                                                      const ushort* __restrict__ aggw,
                                                      const float* __restrict__ att,
                                                      const float* __restrict__ bias,
                                                      float* __restrict__ out) {
    __shared__ ushort lds[10 * 66 * 64];         // 84480 B -> 1 block/CU

    int bid = blockIdx.x;
    int b  = (bid & 7) * 4 + (bid >> 6);         // same-sample blocks on one XCD
    int rt = (bid >> 3) & 7;
    int y0 = rt * 8;

    int tid = threadIdx.x;
    int l = tid & 63, wn = tid >> 6;             // wave wn: output rows y0+2wn, y0+2wn+1
    int l31 = l & 31, lhi = l >> 5;

    const ushort* Ab = aggw + (size_t)b * 147456 + (size_t)l * 8;
    const ushort* xTb = xT + ((size_t)b * 66 + y0) * 66 * 128;

    f32x16 acc[4][4];
#pragma unroll
    for (int m = 0; m < 4; ++m)
#pragma unroll
        for (int n = 0; n < 4; ++n)
#pragma unroll
            for (int q = 0; q < 16; ++q) acc[m][n][q] = 0.f;

    // precomputed swizzle for B reads: c = p*32 + l31 + kw
    int swp[2][3];
#pragma unroll
    for (int p = 0; p < 2; ++p)
#pragma unroll
        for (int kw = 0; kw < 3; ++kw) {
            int c = p * 32 + l31 + kw;
            swp[p][kw] = (((c ^ (c >> 3)) & 7) ^ lhi);
        }

#pragma unroll 1
    for (int h = 0; h < 2; ++h) {
        if (h) __syncthreads();
        // ---- DMA stage: 5280 chunks of 16B (10*66 rc x 8 slots) ----
        for (int i = wn; i < 83; i += 4) {
            int chunk = i * 64 + l;
            if (chunk < 5280) {
                int rc = chunk >> 3;
                int r = rc / 66;
                int c = rc - r * 66;
                int sw = (c ^ (c >> 3)) & 7;
                const ushort* src = xTb + ((size_t)r * 66 + c) * 128 + h * 64 + (((l & 7) ^ sw) << 3);
                dma16(src, &lds[(size_t)rc * 64 + (l & 7) * 8]);
            }
        }
        __syncthreads();

        // ---- 36 K-steps (9 taps x 4 ic-blocks of 16) ----
#pragma unroll
        for (int s = 0; s < 9; ++s) {
            const int kh = s / 3, kw = s % 3;
#pragma unroll
            for (int icb = 0; icb < 4; ++icb) {
                int cid0 = ((h * 9 + s) * 4 + icb) * 4;
                bf16x8 a[4];
#pragma unroll
                for (int m = 0; m < 4; ++m)
                    a[m] = *(const bf16x8*)(Ab + (size_t)(cid0 + m) * 512);
                bf16x8 bb[4];
#pragma unroll
                for (int nb = 0; nb < 4; ++nb) {
                    int r = 2 * wn + (nb >> 1) + kh;
                    int c = (nb & 1) * 32 + l31 + kw;
                    int slot = swp[nb & 1][kw] ^ (icb << 1);
                    bb[nb] = *(const bf16x8*)&lds[((r * 66 + c) << 6) + (slot << 3)];
                }
#pragma unroll
                for (int m = 0; m < 4; ++m)
#pragma unroll
                    for (int nb = 0; nb < 4; ++nb)
                        acc[m][nb] = __builtin_amdgcn_mfma_f32_32x32x16_bf16(a[m], bb[nb], acc[m][nb], 0, 0, 0);
            }
        }
    }

    // ---- epilogue: + att@bias, store ----
    float a0 = att[b * 4 + 0], a1 = att[b * 4 + 1], a2 = att[b * 4 + 2], a3 = att[b * 4 + 3];
#pragma unroll
    for (int m = 0; m < 4; ++m)
#pragma unroll
        for (int q = 0; q < 16; ++q) {
            int oc = m * 32 + (q & 3) + 8 * (q >> 2) + 4 * lhi;
            float ab = a0 * bias[oc] + a1 * bias[128 + oc] + a2 * bias[256 + oc] + a3 * bias[384 + oc];
#pragma unroll
            for (int nb = 0; nb < 4; ++nb) {
                int y = y0 + 2 * wn + (nb >> 1);
                out[(((size_t)b * 128 + oc) * 64 + y) * 64 + (nb & 1) * 32 + l31] = acc[m][nb][q] + ab;
            }
        }
}

// ---------------------------------------------------------------------------
extern "C" void kernel_launch(void* const* d_in, const int* in_sizes, int n_in,
                              void* d_out, int out_size, void* d_ws, size_t ws_size,
                              hipStream_t stream) {
    const float* x      = (const float*)d_in[0];
    const float* weight = (const float*)d_in[1];
    const float* bias   = (const float*)d_in[2];
    const float* se_w1  = (const float*)d_in[3];
    const float* gn1_s  = (const float*)d_in[4];
    const float* gn1_b  = (const float*)d_in[5];
    const float* se_w2  = (const float*)d_in[6];
    const float* gn2_s  = (const float*)d_in[7];
    const float* gn2_b  = (const float*)d_in[8];
    float* out = (float*)d_out;

    // workspace layout
    float*  att     = (float*)((char*)d_ws + 16384);            // 512 B
    float*  partial = (float*)((char*)d_ws + 65536);            // 1 MB (consumed by sefuse, then reused)
    ushort* aggw    = (ushort*)((char*)d_ws + 65536);           // 9.44 MB (written after sefuse)
    ushort* xT      = (ushort*)((char*)d_ws + 10485760);        // 35.7 MB  (total ~46.2 MB)

    transpose_kernel<<<2048, 256, 0, stream>>>(x, xT, partial);
    sefuse_kernel<<<32, 256, 0, stream>>>(partial, se_w1, gn1_s, gn1_b, se_w2, gn2_s, gn2_b, att);
    aggw_kernel<<<72, 256, 0, stream>>>(weight, att, aggw);
    conv_kernel<<<256, 256, 0, stream>>>(xT, aggw, att, bias, out);
}

// Round 5
// 88.945 us; speedup vs baseline: 1.8984x; 1.8984x over previous
//
#include <hip/hip_runtime.h>
#include <hip/hip_bf16.h>
#include <math.h>
#include <stdint.h>

#define EPS 1e-5f

typedef __attribute__((ext_vector_type(8))) short bf16x8;
typedef __attribute__((ext_vector_type(16))) float f32x16;

__device__ __forceinline__ ushort f2bf(float f) {
    union { float f; unsigned u; } v; v.f = f;
    unsigned r = (v.u + 0x7FFFu + ((v.u >> 16) & 1u)) >> 16;
    return (ushort)r;
}

__device__ __forceinline__ void dma16(const void* g, void* l) {
    __builtin_amdgcn_global_load_lds(
        (__attribute__((address_space(1))) const void*)(uintptr_t)g,
        (__attribute__((address_space(3))) void*)(uintptr_t)l,
        16, 0, 0);
}

// ---------------------------------------------------------------------------
// Kernel 1: transpose x -> xT[b][y 66][c 66][ic 128] bf16 (borders zero),
// plus pooling partials [b][y][ic].  grid = 2048, XCD-grouped by sample.
// ---------------------------------------------------------------------------
__global__ __launch_bounds__(256) void transpose_kernel(const float* __restrict__ x,
                                                        ushort* __restrict__ xT,
                                                        float* __restrict__ partial) {
    __shared__ float T[128][65];
    int bid = blockIdx.x;
    int b = (bid & 7) * 4 + (bid >> 9);
    int y = (bid >> 3) & 63;
    int t = threadIdx.x;

    int ic2 = t >> 1, half = t & 1;
    const float4* src = (const float4*)(x + (((size_t)b * 128 + ic2) * 64 + y) * 64 + half * 32);
    float s = 0.f;
#pragma unroll
    for (int i = 0; i < 8; ++i) {
        float4 v = src[i];
        int c0 = half * 32 + i * 4;
        T[ic2][c0] = v.x; T[ic2][c0 + 1] = v.y; T[ic2][c0 + 2] = v.z; T[ic2][c0 + 3] = v.w;
        s += v.x + v.y + v.z + v.w;
    }
    s += __shfl_xor(s, 1, 64);
    if (half == 0) partial[((size_t)b * 64 + y) * 128 + ic2] = s;
    __syncthreads();

    // phase 2: col = t&63 -> LDS reads 2-way (free), writes 64B/thread
    int col = t & 63, icq = t >> 6;
    uint pk[16];
#pragma unroll
    for (int j = 0; j < 16; ++j) {
        float f0 = T[icq * 32 + 2 * j][col];
        float f1 = T[icq * 32 + 2 * j + 1][col];
        pk[j] = (uint)f2bf(f0) | ((uint)f2bf(f1) << 16);
    }
    ushort* dst = xT + (((size_t)(b * 66 + y + 1)) * 66 + col + 1) * 128 + icq * 32;
    ((uint4*)dst)[0] = make_uint4(pk[0], pk[1], pk[2], pk[3]);
    ((uint4*)dst)[1] = make_uint4(pk[4], pk[5], pk[6], pk[7]);
    ((uint4*)dst)[2] = make_uint4(pk[8], pk[9], pk[10], pk[11]);
    ((uint4*)dst)[3] = make_uint4(pk[12], pk[13], pk[14], pk[15]);

    uint4 z = make_uint4(0, 0, 0, 0);
    if (y == 0) {
        uint4* row0 = (uint4*)(xT + ((size_t)b * 66 + 0) * 66 * 128);
        for (int i = t; i < 1056; i += 256) row0[i] = z;
    }
    if (y == 63) {
        uint4* row65 = (uint4*)(xT + ((size_t)b * 66 + 65) * 66 * 128);
        for (int i = t; i < 1056; i += 256) row65[i] = z;
    }
    if (t < 32) {
        int c = (t >> 4) * 65;
        int i = t & 15;
        *(uint4*)(xT + (((size_t)(b * 66 + y + 1)) * 66 + c) * 128 + i * 8) = z;
    }
}

// ---------------------------------------------------------------------------
// Kernel 2: fused reduce + SE MLP -> att[32,4].  grid = 32.
// ---------------------------------------------------------------------------
__global__ __launch_bounds__(256) void sefuse_kernel(const float* __restrict__ partial,
                                                     const float* __restrict__ se_w1,
                                                     const float* __restrict__ gn1_s, const float* __restrict__ gn1_b,
                                                     const float* __restrict__ se_w2,
                                                     const float* __restrict__ gn2_s, const float* __restrict__ gn2_b,
                                                     float* __restrict__ att) {
    __shared__ float sA[256];
    __shared__ float pl[128];
    __shared__ float h1s[8];
    int b = blockIdx.x;
    int t = threadIdx.x;
    int ic = t & 127, hf = t >> 7;

    const float* p = partial + ((size_t)b * 64 + hf * 32) * 128 + ic;
    float s = 0.f;
#pragma unroll
    for (int k = 0; k < 32; ++k) s += p[k * 128];
    sA[t] = s;
    __syncthreads();
    if (t < 128) pl[t] = (sA[t] + sA[t + 128]) * (1.0f / 4096.0f);
    __syncthreads();
    if (t < 8) {
        float s1 = 0.f;
        for (int c = 0; c < 128; ++c) s1 += pl[c] * se_w1[t * 128 + c];
        h1s[t] = s1;
    }
    __syncthreads();
    if (t == 0) {
        float h1[8];
#pragma unroll
        for (int j = 0; j < 8; ++j) h1[j] = h1s[j];
        float m = 0.f;
#pragma unroll
        for (int j = 0; j < 8; ++j) m += h1[j];
        m *= 0.125f;
        float var = 0.f;
#pragma unroll
        for (int j = 0; j < 8; ++j) { float d = h1[j] - m; var += d * d; }
        var *= 0.125f;
        float inv = rsqrtf(var + EPS);
#pragma unroll
        for (int j = 0; j < 8; ++j) {
            float tt = (h1[j] - m) * inv * gn1_s[j] + gn1_b[j];
            float sp = (tt > 20.f) ? tt : log1pf(expf(tt));
            h1[j] = tt * tanhf(sp);
        }
        float h2[4];
#pragma unroll
        for (int k = 0; k < 4; ++k) {
            float s2 = 0.f;
#pragma unroll
            for (int j = 0; j < 8; ++j) s2 += h1[j] * se_w2[k * 8 + j];
            h2[k] = s2;
        }
        float m2 = 0.25f * (h2[0] + h2[1] + h2[2] + h2[3]);
        float v2 = 0.f;
#pragma unroll
        for (int k = 0; k < 4; ++k) { float d = h2[k] - m2; v2 += d * d; }
        v2 *= 0.25f;
        float inv2 = rsqrtf(v2 + EPS);
#pragma unroll
        for (int k = 0; k < 4; ++k) {
            float tt = (h2[k] - m2) * inv2 * gn2_s[k] + gn2_b[k];
            att[b * 4 + k] = 1.0f / (1.0f + expf(-tt));
        }
    }
}

// ---------------------------------------------------------------------------
// Kernel 3: aggregate weights -> bf16, rotated-chunk A layout.
// Per (b, tap= h*9+s): 16 KB block of 1024 chunks (16B).  Chunk for (oc, g):
// index = oc*8 + ((g + oc) & 7), content = ic [h*64+g*8, +8) of row oc.
// grid = 288 (4 replicas x 72); replica handles 8 samples.
// ---------------------------------------------------------------------------
__global__ __launch_bounds__(256) void aggw_kernel(const float* __restrict__ weight,
                                                   const float* __restrict__ att,
                                                   ushort* __restrict__ aggw) {
    int tq = (blockIdx.x % 72) * 256 + threadIdx.x;   // chunk id in sample: 0..18431
    int rep = blockIdx.x / 72;                         // 0..3 -> samples rep*8..rep*8+7
    int tap = tq >> 10;                                // 0..17
    int within = tq & 1023;
    int oc = within >> 3;
    int p = within & 7;
    int g = (p - oc) & 7;
    int h = tap / 9, s = tap % 9;
    int ic0 = h * 64 + g * 8;

    float wv[4][8];
#pragma unroll
    for (int k = 0; k < 4; ++k)
#pragma unroll
        for (int j = 0; j < 8; ++j)
            wv[k][j] = weight[(((size_t)(k * 128 + oc)) * 128 + ic0 + j) * 9 + s];

    for (int b = rep * 8; b < rep * 8 + 8; ++b) {
        float a0 = att[b * 4 + 0], a1 = att[b * 4 + 1], a2 = att[b * 4 + 2], a3 = att[b * 4 + 3];
        uint pk[4];
#pragma unroll
        for (int q = 0; q < 4; ++q) {
            float f0 = a0 * wv[0][2 * q] + a1 * wv[1][2 * q] + a2 * wv[2][2 * q] + a3 * wv[3][2 * q];
            float f1 = a0 * wv[0][2 * q + 1] + a1 * wv[1][2 * q + 1] + a2 * wv[2][2 * q + 1] + a3 * wv[3][2 * q + 1];
            pk[q] = (uint)f2bf(f0) | ((uint)f2bf(f1) << 16);
        }
        *(uint4*)(aggw + (size_t)b * 147456 + (size_t)tq * 8) = make_uint4(pk[0], pk[1], pk[2], pk[3]);
    }
}

// ---------------------------------------------------------------------------
// Kernel 4: implicit-GEMM conv, mfma_f32_32x32x16_bf16.
// grid 512 = 32 b * 16 tiles (4 rows); block 256 = 4 waves (wm: oc-64, wn: row-pair).
// Wave = 64 oc x 128 px, acc[2][4].  B in LDS (rotation slots), A in registers
// with depth-1 tap prefetch.  3 __syncthreads per block.
// ---------------------------------------------------------------------------
__global__ __launch_bounds__(256, 2) void conv_kernel(const ushort* __restrict__ xT,
                                                      const ushort* __restrict__ aggw,
                                                      const float* __restrict__ att,
                                                      const float* __restrict__ bias,
                                                      float* __restrict__ out) {
    __shared__ ushort ldsB[396 * 64];                 // 6 rows x 66 cols x 8 slots x 16B = 50688 B

    int bid = blockIdx.x;
    int xcd = bid & 7;
    int idx = bid >> 3;                                // 0..63
    int b = xcd * 4 + (idx >> 4);                      // 4 samples per XCD
    int tile = idx & 15;
    int y0 = tile * 4;

    int tid = threadIdx.x;
    int l = tid & 63, w = tid >> 6;
    int wm = w >> 1, wn = w & 1;
    int l31 = l & 31, lhi = l >> 5;

    const ushort* xTb = xT + ((size_t)(b * 66 + y0)) * 66 * 128;  // halo rows y0..y0+5
    const ushort* Asmp = aggw + (size_t)b * 147456;

    // per-lane A pointers/rotations: oc(mi) = wm*64 + mi*32 + l31
    const ushort* ptrA[2];
    int rotA[2];
#pragma unroll
    for (int mi = 0; mi < 2; ++mi) {
        int oc = wm * 64 + mi * 32 + l31;
        ptrA[mi] = Asmp + oc * 64;
        rotA[mi] = (lhi + oc) & 7;
    }
    // B cell bases: nb = rs*2 + ch
    int CB[4];
#pragma unroll
    for (int nb = 0; nb < 4; ++nb) {
        int rs = nb >> 1, ch = nb & 1;
        CB[nb] = (2 * wn + rs) * 66 + ch * 32 + l31;
    }
    int rotB = (l31 + lhi) & 7;

    f32x16 acc[2][4];
#pragma unroll
    for (int mi = 0; mi < 2; ++mi)
#pragma unroll
        for (int nb = 0; nb < 4; ++nb)
#pragma unroll
            for (int q = 0; q < 16; ++q) acc[mi][nb][q] = 0.f;

    // ---- prefetch A tap 0 ----
    bf16x8 a[2][4];
#pragma unroll
    for (int mi = 0; mi < 2; ++mi)
#pragma unroll
        for (int icb = 0; icb < 4; ++icb)
            a[mi][icb] = *(const bf16x8*)(ptrA[mi] + (((rotA[mi] + 2 * icb) & 7) << 3));

    // ---- stage B(h=0) ----
#pragma unroll
    for (int i = 0; i < 13; ++i) {
        int k = i * 256 + tid;
        if (k < 3168) {
            int rc = k >> 3;
            int c = rc % 66;
            int g = ((k & 7) - c) & 7;
            dma16(xTb + (size_t)rc * 128 + (g << 3), &ldsB[(size_t)k * 8]);
        }
    }
    __syncthreads();

    for (int hs = 0; hs < 18; ++hs) {
        int s = (hs >= 9) ? hs - 9 : hs;
        int kh = s / 3, kw = s - kh * 3;
        int celladd = kh * 66 + kw;
        const ushort* Anext = Asmp + (size_t)(hs + 1) * 8192;
#pragma unroll
        for (int icb = 0; icb < 4; ++icb) {
            int slotb = (rotB + 2 * icb + kw) & 7;
            bf16x8 bb[4];
#pragma unroll
            for (int nb = 0; nb < 4; ++nb) {
                int cell = CB[nb] + celladd;
                bb[nb] = *(const bf16x8*)&ldsB[(cell << 6) + (slotb << 3)];
            }
#pragma unroll
            for (int mi = 0; mi < 2; ++mi)
#pragma unroll
                for (int nb = 0; nb < 4; ++nb)
                    acc[mi][nb] = __builtin_amdgcn_mfma_f32_32x32x16_bf16(a[mi][icb], bb[nb], acc[mi][nb], 0, 0, 0);
            // prefetch this frag for next tap (regs just freed)
            if (hs < 17) {
#pragma unroll
                for (int mi = 0; mi < 2; ++mi) {
                    int oc64 = (wm * 64 + mi * 32 + l31) * 64;
                    a[mi][icb] = *(const bf16x8*)(Anext + oc64 + (((rotA[mi] + 2 * icb) & 7) << 3));
                }
            }
        }
        if (hs == 8) {
            __syncthreads();
#pragma unroll
            for (int i = 0; i < 13; ++i) {
                int k = i * 256 + tid;
                if (k < 3168) {
                    int rc = k >> 3;
                    int c = rc % 66;
                    int g = ((k & 7) - c) & 7;
                    dma16(xTb + (size_t)rc * 128 + 64 + (g << 3), &ldsB[(size_t)k * 8]);
                }
            }
            __syncthreads();
        }
    }

    // ---- epilogue: + att@bias, store ----
    float a0 = att[b * 4 + 0], a1 = att[b * 4 + 1], a2 = att[b * 4 + 2], a3 = att[b * 4 + 3];
#pragma unroll
    for (int mi = 0; mi < 2; ++mi)
#pragma unroll
        for (int q = 0; q < 16; ++q) {
            int oc = wm * 64 + mi * 32 + (q & 3) + 8 * (q >> 2) + 4 * lhi;
            float ab = a0 * bias[oc] + a1 * bias[128 + oc] + a2 * bias[256 + oc] + a3 * bias[384 + oc];
#pragma unroll
            for (int nb = 0; nb < 4; ++nb) {
                int y = y0 + 2 * wn + (nb >> 1);
                out[(((size_t)b * 128 + oc) * 64 + y) * 64 + (nb & 1) * 32 + l31] = acc[mi][nb][q] + ab;
            }
        }
}

// ---------------------------------------------------------------------------
extern "C" void kernel_launch(void* const* d_in, const int* in_sizes, int n_in,
                              void* d_out, int out_size, void* d_ws, size_t ws_size,
                              hipStream_t stream) {
    const float* x      = (const float*)d_in[0];
    const float* weight = (const float*)d_in[1];
    const float* bias   = (const float*)d_in[2];
    const float* se_w1  = (const float*)d_in[3];
    const float* gn1_s  = (const float*)d_in[4];
    const float* gn1_b  = (const float*)d_in[5];
    const float* se_w2  = (const float*)d_in[6];
    const float* gn2_s  = (const float*)d_in[7];
    const float* gn2_b  = (const float*)d_in[8];
    float* out = (float*)d_out;

    float*  att     = (float*)((char*)d_ws + 16384);            // 512 B
    float*  partial = (float*)((char*)d_ws + 65536);            // 1 MB (consumed by sefuse, then reused)
    ushort* aggw    = (ushort*)((char*)d_ws + 65536);           // 9.44 MB (written after sefuse reads partial)
    ushort* xT      = (ushort*)((char*)d_ws + 10485760);        // 35.7 MB

    transpose_kernel<<<2048, 256, 0, stream>>>(x, xT, partial);
    sefuse_kernel<<<32, 256, 0, stream>>>(partial, se_w1, gn1_s, gn1_b, se_w2, gn2_s, gn2_b, att);
    aggw_kernel<<<288, 256, 0, stream>>>(weight, att, aggw);
    conv_kernel<<<512, 256, 0, stream>>>(xT, aggw, att, bias, out);
}